// Round 2
// baseline (743.044 us; speedup 1.0000x reference)
//
#include <hip/hip_runtime.h>
#include <hip/hip_bf16.h>

#define TT 2048
#define HH 1024
#define FF 4096
#define NE 8
#define BK 64

typedef __attribute__((ext_vector_type(4))) float f4;
typedef __attribute__((ext_vector_type(4))) short s4;
typedef __attribute__((ext_vector_type(8))) short s8;

static __device__ __forceinline__ short f2bf(float x) {
  union { __hip_bfloat16 b; short s; } u;
  u.b = __float2bfloat16(x);
  return u.s;
}

// async global->LDS, 16B per lane; lds dest wave-uniform base + lane*16
static __device__ __forceinline__ void gload16(const void* g, void* l) {
  __builtin_amdgcn_global_load_lds(
      (const __attribute__((address_space(1))) void*)g,
      (__attribute__((address_space(3))) void*)l, 16, 0, 0);
}

// ---------------- fp32 -> bf16 streaming convert (8 elems/thread/iter)
__global__ __launch_bounds__(256) void k_cvt(
    const float* __restrict__ src, __hip_bfloat16* __restrict__ dst, int n8)
{
  int i = blockIdx.x * blockDim.x + threadIdx.x;
  const int stride = gridDim.x * blockDim.x;
  for (; i < n8; i += stride) {
    f4 a = ((const f4*)src)[2 * i];
    f4 b = ((const f4*)src)[2 * i + 1];
    s8 o = { f2bf(a.x), f2bf(a.y), f2bf(a.z), f2bf(a.w),
             f2bf(b.x), f2bf(b.y), f2bf(b.z), f2bf(b.w) };
    ((s8*)dst)[i] = o;
  }
}

// ---------------- Router: logits -> softcap -> softmax -> top2 -> expert lists
__global__ __launch_bounds__(256) void k_router(
    const float* __restrict__ h, const float* __restrict__ gw,
    int* __restrict__ cnt, int* __restrict__ tok, float* __restrict__ wt)
{
  const int lane = threadIdx.x & 63;
  const int wid  = threadIdx.x >> 6;
  const int t = blockIdx.x * 4 + wid;
  const float* hr = h + (size_t)t * HH;

  float acc[NE];
#pragma unroll
  for (int e = 0; e < NE; e++) acc[e] = 0.f;
#pragma unroll 4
  for (int i = 0; i < HH / 64; i++) {
    float hv = hr[lane + (i << 6)];
#pragma unroll
    for (int e = 0; e < NE; e++) acc[e] += hv * gw[e * HH + lane + (i << 6)];
  }
#pragma unroll
  for (int e = 0; e < NE; e++) {
    float v = acc[e];
#pragma unroll
    for (int s = 32; s > 0; s >>= 1) v += __shfl_xor(v, s);
    acc[e] = v;
  }
  if (lane == 0) {
    float p[NE];
    float m = -1e30f;
#pragma unroll
    for (int e = 0; e < NE; e++) {
      p[e] = 30.f * tanhf(acc[e] * (1.f / 30.f));
      m = fmaxf(m, p[e]);
    }
    float s = 0.f;
#pragma unroll
    for (int e = 0; e < NE; e++) { p[e] = expf(p[e] - m); s += p[e]; }
    const float inv = 1.f / s;
    int e1 = 0;
#pragma unroll
    for (int e = 1; e < NE; e++) if (p[e] > p[e1]) e1 = e;
    int e2 = (e1 == 0) ? 1 : 0;
#pragma unroll
    for (int e = 0; e < NE; e++) if (e != e1 && p[e] > p[e2]) e2 = e;

    int pos1 = atomicAdd(&cnt[e1], 1);
    tok[e1 * TT + pos1] = t;
    wt [e1 * TT + pos1] = p[e1] * inv;
    int pos2 = atomicAdd(&cnt[e2], 1);
    tok[e2 * TT + pos2] = t;
    wt [e2 * TT + pos2] = p[e2] * inv;
  }
}

// ---------------- FFN1 (two passes, m97 structure: 128x128 tile, BK=64,
// 4 waves each 64x64, linear LDS + global_load_lds dwordx4)
// GPASS=false: act = x @ W3^T (store bf16 u)
// GPASS=true : act = gelu(x @ W1^T) * act   (RMW)
template<bool GPASS>
__global__ __launch_bounds__(256) void k_ffn1(
    const __hip_bfloat16* __restrict__ hb, const __hip_bfloat16* __restrict__ wb,
    const int* __restrict__ cnt, const int* __restrict__ tok,
    __hip_bfloat16* __restrict__ act)
{
  const int e  = blockIdx.z;
  const int mt = blockIdx.y;
  const int nt = blockIdx.x;
  const int ce = cnt[e];
  if (mt * 128 >= ce) return;
  int base = 0;
  for (int i = 0; i < e; i++) base += cnt[i];

  __shared__ short As[128 * BK];   // 16 KB, linear (gload_lds requires it)
  __shared__ short Bs[128 * BK];   // 16 KB

  const int tid  = threadIdx.x;
  const int lane = tid & 63;
  const int wid  = tid >> 6;
  const int wm   = wid >> 1;   // 2x2 waves, 64x64 each
  const int wn   = wid & 1;

  // staging: wave w, instr i covers LDS rows i*32 + w*8 .. +7, 128B/row
  const int srow = (wid << 3) + (lane >> 3);
  const int scol = (lane & 7) << 3;
  const __hip_bfloat16* asrc[4];
#pragma unroll
  for (int i = 0; i < 4; i++) {
    int pos = mt * 128 + i * 32 + srow;
    int tk  = tok[e * TT + min(pos, ce - 1)];
    asrc[i] = hb + (size_t)tk * HH + scol;
  }
  const __hip_bfloat16* bsrc[4];
#pragma unroll
  for (int i = 0; i < 4; i++) {
    int fr = nt * 128 + i * 32 + srow;
    bsrc[i] = wb + ((size_t)e * FF + fr) * HH + scol;
  }

  f4 acc[4][4];
#pragma unroll
  for (int i = 0; i < 4; i++)
#pragma unroll
    for (int j = 0; j < 4; j++) { f4 z = {0.f,0.f,0.f,0.f}; acc[i][j] = z; }

  for (int kk = 0; kk < HH; kk += BK) {
#pragma unroll
    for (int i = 0; i < 4; i++) {
      gload16(asrc[i] + kk, &As[(i * 32 + (wid << 3)) * BK]);
      gload16(bsrc[i] + kk, &Bs[(i * 32 + (wid << 3)) * BK]);
    }
    __syncthreads();
#pragma unroll
    for (int ks = 0; ks < 2; ks++) {
      const int ko = ks * 32 + ((lane >> 4) << 3);
      s8 af[4], bf_[4];
#pragma unroll
      for (int i = 0; i < 4; i++)
        af[i]  = *(const s8*)&As[(wm * 64 + i * 16 + (lane & 15)) * BK + ko];
#pragma unroll
      for (int j = 0; j < 4; j++)
        bf_[j] = *(const s8*)&Bs[(wn * 64 + j * 16 + (lane & 15)) * BK + ko];
#pragma unroll
      for (int i = 0; i < 4; i++)
#pragma unroll
        for (int j = 0; j < 4; j++)
          acc[i][j] = __builtin_amdgcn_mfma_f32_16x16x32_bf16(af[i], bf_[j], acc[i][j], 0, 0, 0);
    }
    __syncthreads();
  }

  const int orow0 = wm * 64 + ((lane >> 4) << 2);
  const int ocol0 = nt * 128 + wn * 64 + (lane & 15);
#pragma unroll
  for (int i = 0; i < 4; i++)
#pragma unroll
    for (int r = 0; r < 4; r++) {
      int rr = mt * 128 + orow0 + i * 16 + r;
      if (rr < ce) {
        size_t rowoff = (size_t)(base + rr) * FF + ocol0;
#pragma unroll
        for (int j = 0; j < 4; j++) {
          float v = acc[i][j][r];
          if (GPASS) {
            float u = __bfloat162float(act[rowoff + j * 16]);
            v = 0.5f * v * (1.f + erff(v * 0.70710678118f)) * u;
          }
          act[rowoff + j * 16] = __float2bfloat16(v);
        }
      }
    }
}

// ---------------- FFN2: out[tok,:] += wt * (act @ W2^T), split-K x4
__global__ __launch_bounds__(256) void k_ffn2(
    const __hip_bfloat16* __restrict__ act, const __hip_bfloat16* __restrict__ w2b,
    const int* __restrict__ cnt, const int* __restrict__ tok,
    const float* __restrict__ wt, float* __restrict__ out)
{
  const int e  = blockIdx.z >> 2;
  const int sk = blockIdx.z & 3;     // K chunk: [sk*1024, sk*1024+1024)
  const int mt = blockIdx.y;
  const int nt = blockIdx.x;
  const int ce = cnt[e];
  if (mt * 128 >= ce) return;
  int base = 0;
  for (int i = 0; i < e; i++) base += cnt[i];

  __shared__ short As[128 * BK];
  __shared__ short Bs[128 * BK];

  const int tid  = threadIdx.x;
  const int lane = tid & 63;
  const int wid  = tid >> 6;
  const int wm   = wid >> 1;
  const int wn   = wid & 1;

  const int srow = (wid << 3) + (lane >> 3);
  const int scol = (lane & 7) << 3;
  const __hip_bfloat16* asrc[4];
#pragma unroll
  for (int i = 0; i < 4; i++) {
    int pos = mt * 128 + i * 32 + srow;
    int rc  = min(pos, ce - 1);
    asrc[i] = act + (size_t)(base + rc) * FF + (sk << 10) + scol;
  }
  const __hip_bfloat16* bsrc[4];
#pragma unroll
  for (int i = 0; i < 4; i++) {
    int hr = nt * 128 + i * 32 + srow;
    bsrc[i] = w2b + ((size_t)e * HH + hr) * FF + (sk << 10) + scol;
  }

  f4 acc[4][4];
#pragma unroll
  for (int i = 0; i < 4; i++)
#pragma unroll
    for (int j = 0; j < 4; j++) { f4 z = {0.f,0.f,0.f,0.f}; acc[i][j] = z; }

  for (int kk = 0; kk < 1024; kk += BK) {
#pragma unroll
    for (int i = 0; i < 4; i++) {
      gload16(asrc[i] + kk, &As[(i * 32 + (wid << 3)) * BK]);
      gload16(bsrc[i] + kk, &Bs[(i * 32 + (wid << 3)) * BK]);
    }
    __syncthreads();
#pragma unroll
    for (int ks = 0; ks < 2; ks++) {
      const int ko = ks * 32 + ((lane >> 4) << 3);
      s8 af[4], bf_[4];
#pragma unroll
      for (int i = 0; i < 4; i++)
        af[i]  = *(const s8*)&As[(wm * 64 + i * 16 + (lane & 15)) * BK + ko];
#pragma unroll
      for (int j = 0; j < 4; j++)
        bf_[j] = *(const s8*)&Bs[(wn * 64 + j * 16 + (lane & 15)) * BK + ko];
#pragma unroll
      for (int i = 0; i < 4; i++)
#pragma unroll
        for (int j = 0; j < 4; j++)
          acc[i][j] = __builtin_amdgcn_mfma_f32_16x16x32_bf16(af[i], bf_[j], acc[i][j], 0, 0, 0);
    }
    __syncthreads();
  }

  const int orow0 = wm * 64 + ((lane >> 4) << 2);
  const int ocol0 = nt * 128 + wn * 64 + (lane & 15);
#pragma unroll
  for (int i = 0; i < 4; i++)
#pragma unroll
    for (int r = 0; r < 4; r++) {
      int rr = mt * 128 + orow0 + i * 16 + r;
      if (rr < ce) {
        int   tkn = tok[e * TT + rr];
        float w   = wt [e * TT + rr];
        float* orow = out + (size_t)tkn * HH + ocol0;
#pragma unroll
        for (int j = 0; j < 4; j++)
          atomicAdd(&orow[j * 16], acc[i][j][r] * w);
      }
    }
}

extern "C" void kernel_launch(void* const* d_in, const int* in_sizes, int n_in,
                              void* d_out, int out_size, void* d_ws, size_t ws_size,
                              hipStream_t stream)
{
  (void)in_sizes; (void)n_in; (void)ws_size;
  const float* h  = (const float*)d_in[0];
  const float* gw = (const float*)d_in[1];
  const float* w1 = (const float*)d_in[2];
  const float* w2 = (const float*)d_in[3];
  const float* w3 = (const float*)d_in[4];
  float* out = (float*)d_out;

  // ws layout (needs ~239 MB)
  char* ws = (char*)d_ws;
  int*   cnt = (int*)ws;                             // 32 B
  int*   tok = (int*)(ws + 1024);                    // 64 KB
  float* wtp = (float*)(ws + 1024 + 65536);          // 64 KB
  __hip_bfloat16* act = (__hip_bfloat16*)(ws + 262144);            // 32 MB
  __hip_bfloat16* hb  = (__hip_bfloat16*)(ws + 262144 + 33554432); // 4 MB
  __hip_bfloat16* w1b = hb  + (size_t)TT * HH;                     // 64 MB
  __hip_bfloat16* w3b = w1b + (size_t)NE * FF * HH;                // 64 MB
  __hip_bfloat16* w2b = w3b + (size_t)NE * FF * HH;                // 64 MB

  hipMemsetAsync(cnt, 0, 32, stream);
  hipMemsetAsync(d_out, 0, (size_t)out_size * sizeof(float), stream);

  k_cvt<<<dim3(1024), dim3(256), 0, stream>>>(h,  hb,  TT * HH / 8);
  k_cvt<<<dim3(2048), dim3(256), 0, stream>>>(w1, w1b, NE * FF * HH / 8);
  k_cvt<<<dim3(2048), dim3(256), 0, stream>>>(w3, w3b, NE * FF * HH / 8);
  k_cvt<<<dim3(2048), dim3(256), 0, stream>>>(w2, w2b, NE * HH * FF / 8);

  k_router<<<dim3(TT / 4), dim3(256), 0, stream>>>(h, gw, cnt, tok, wtp);

  k_ffn1<false><<<dim3(FF / 128, 16, NE), dim3(256), 0, stream>>>(hb, w3b, cnt, tok, act);
  k_ffn1<true ><<<dim3(FF / 128, 16, NE), dim3(256), 0, stream>>>(hb, w1b, cnt, tok, act);
  k_ffn2<<<dim3(HH / 128, 16, NE * 4), dim3(256), 0, stream>>>(act, w2b, cnt, tok, wtp, out);
}

// Round 3
// 715.884 us; speedup vs baseline: 1.0379x; 1.0379x over previous
//
#include <hip/hip_runtime.h>
#include <hip/hip_bf16.h>

#define TT 2048
#define HH 1024
#define FF 4096
#define NE 8
#define BK 64

typedef __attribute__((ext_vector_type(4))) float f4;
typedef __attribute__((ext_vector_type(4))) short s4;
typedef __attribute__((ext_vector_type(8))) short s8;

static __device__ __forceinline__ short f2bf(float x) {
  union { __hip_bfloat16 b; short s; } u;
  u.b = __float2bfloat16(x);
  return u.s;
}

// async global->LDS, 16B/lane; LDS dest = wave-uniform base + lane*16
static __device__ __forceinline__ void gload16(const void* g, void* l) {
  __builtin_amdgcn_global_load_lds(
      (const __attribute__((address_space(1))) void*)g,
      (__attribute__((address_space(3))) void*)l, 16, 0, 0);
}

// ---------------- fp32 -> bf16 streaming convert
__global__ __launch_bounds__(256) void k_cvt(
    const float* __restrict__ src, __hip_bfloat16* __restrict__ dst, int n8)
{
  int i = blockIdx.x * blockDim.x + threadIdx.x;
  const int stride = gridDim.x * blockDim.x;
  for (; i < n8; i += stride) {
    f4 a = ((const f4*)src)[2 * i];
    f4 b = ((const f4*)src)[2 * i + 1];
    s8 o = { f2bf(a.x), f2bf(a.y), f2bf(a.z), f2bf(a.w),
             f2bf(b.x), f2bf(b.y), f2bf(b.z), f2bf(b.w) };
    ((s8*)dst)[i] = o;
  }
}

// ---------------- Router
__global__ __launch_bounds__(256) void k_router(
    const float* __restrict__ h, const float* __restrict__ gw,
    int* __restrict__ cnt, int* __restrict__ tok, float* __restrict__ wt)
{
  const int lane = threadIdx.x & 63;
  const int wid  = threadIdx.x >> 6;
  const int t = blockIdx.x * 4 + wid;
  const float* hr = h + (size_t)t * HH;

  float acc[NE];
#pragma unroll
  for (int e = 0; e < NE; e++) acc[e] = 0.f;
#pragma unroll 4
  for (int i = 0; i < HH / 64; i++) {
    float hv = hr[lane + (i << 6)];
#pragma unroll
    for (int e = 0; e < NE; e++) acc[e] += hv * gw[e * HH + lane + (i << 6)];
  }
#pragma unroll
  for (int e = 0; e < NE; e++) {
    float v = acc[e];
#pragma unroll
    for (int s = 32; s > 0; s >>= 1) v += __shfl_xor(v, s);
    acc[e] = v;
  }
  if (lane == 0) {
    float p[NE];
    float m = -1e30f;
#pragma unroll
    for (int e = 0; e < NE; e++) {
      p[e] = 30.f * tanhf(acc[e] * (1.f / 30.f));
      m = fmaxf(m, p[e]);
    }
    float s = 0.f;
#pragma unroll
    for (int e = 0; e < NE; e++) { p[e] = expf(p[e] - m); s += p[e]; }
    const float inv = 1.f / s;
    int e1 = 0;
#pragma unroll
    for (int e = 1; e < NE; e++) if (p[e] > p[e1]) e1 = e;
    int e2 = (e1 == 0) ? 1 : 0;
#pragma unroll
    for (int e = 0; e < NE; e++) if (e != e1 && p[e] > p[e2]) e2 = e;

    int pos1 = atomicAdd(&cnt[e1], 1);
    tok[e1 * TT + pos1] = t;
    wt [e1 * TT + pos1] = p[e1] * inv;
    int pos2 = atomicAdd(&cnt[e2], 1);
    tok[e2 * TT + pos2] = t;
    wt [e2 * TT + pos2] = p[e2] * inv;
  }
}

// Swizzled staging column for lane l (elements): chunk (l&7) XOR row (l>>3)&7
#define SWZCOL(l) (((((l) & 7) ^ (((l) >> 3) & 7))) << 3)

// ---------------- FFN1 (2-phase dbuf, counted vmcnt, T2 swizzle)
// GPASS=false: act = x @ W3^T ; GPASS=true: act = gelu(x @ W1^T) * act
template<bool GPASS>
__global__ __launch_bounds__(256) void k_ffn1(
    const __hip_bfloat16* __restrict__ hb, const __hip_bfloat16* __restrict__ wb,
    const int* __restrict__ cnt, const int* __restrict__ tok,
    __hip_bfloat16* __restrict__ act)
{
  const int e  = blockIdx.z;
  const int mt = blockIdx.y;
  const int nt = blockIdx.x;
  const int ce = cnt[e];
  if (mt * 128 >= ce) return;
  int base = 0;
  for (int i = 0; i < e; i++) base += cnt[i];

  __shared__ short As[2][128 * BK];  // 32 KB (dbuf)
  __shared__ short Bs[2][128 * BK];  // 32 KB

  const int tid  = threadIdx.x;
  const int lane = tid & 63;
  const int wid  = tid >> 6;
  const int wm   = wid >> 1;
  const int wn   = wid & 1;

  const int srow = (wid << 3) + (lane >> 3);
  const int scol = SWZCOL(lane);           // pre-swizzled global column
  const __hip_bfloat16* asrc[4];
#pragma unroll
  for (int i = 0; i < 4; i++) {
    int pos = mt * 128 + i * 32 + srow;
    int tk  = tok[e * TT + min(pos, ce - 1)];
    asrc[i] = hb + (size_t)tk * HH + scol;
  }
  const __hip_bfloat16* bsrc[4];
#pragma unroll
  for (int i = 0; i < 4; i++) {
    int fr = nt * 128 + i * 32 + srow;
    bsrc[i] = wb + ((size_t)e * FF + fr) * HH + scol;
  }

  f4 acc[4][4];
#pragma unroll
  for (int i = 0; i < 4; i++)
#pragma unroll
    for (int j = 0; j < 4; j++) { f4 z = {0.f,0.f,0.f,0.f}; acc[i][j] = z; }

#define STAGE1(kk, b)                                                  \
  {                                                                    \
    _Pragma("unroll")                                                  \
    for (int i_ = 0; i_ < 4; i_++) {                                   \
      gload16(asrc[i_] + (kk), &As[b][(i_ * 32 + (wid << 3)) * BK]);   \
      gload16(bsrc[i_] + (kk), &Bs[b][(i_ * 32 + (wid << 3)) * BK]);   \
    }                                                                  \
  }

  const int xorv = lane & 7;            // row&7 for fragment rows
  const int hi   = lane >> 4;           // 0..3
  const int frow = lane & 15;

  STAGE1(0, 0);
  int cur = 0;
  const int NT = HH / BK;               // 16
  for (int t = 0; t < NT; t++) {
    if (t + 1 < NT) {
      STAGE1((t + 1) * BK, cur ^ 1);
      asm volatile("s_waitcnt vmcnt(8)" ::: "memory");
    } else {
      asm volatile("s_waitcnt vmcnt(0)" ::: "memory");
    }
    __builtin_amdgcn_s_barrier();
    __builtin_amdgcn_sched_barrier(0);
#pragma unroll
    for (int ks = 0; ks < 2; ks++) {
      const int col = (((ks << 2) + hi) ^ xorv) << 3;   // swizzled elem col
      s8 af[4], bf_[4];
#pragma unroll
      for (int i = 0; i < 4; i++)
        af[i]  = *(const s8*)&As[cur][(wm * 64 + i * 16 + frow) * BK + col];
#pragma unroll
      for (int j = 0; j < 4; j++)
        bf_[j] = *(const s8*)&Bs[cur][(wn * 64 + j * 16 + frow) * BK + col];
#pragma unroll
      for (int i = 0; i < 4; i++)
#pragma unroll
        for (int j = 0; j < 4; j++)
          acc[i][j] = __builtin_amdgcn_mfma_f32_16x16x32_bf16(af[i], bf_[j], acc[i][j], 0, 0, 0);
    }
    __builtin_amdgcn_sched_barrier(0);
    __builtin_amdgcn_s_barrier();
    cur ^= 1;
  }

  const int orow0 = wm * 64 + ((lane >> 4) << 2);
  const int ocol0 = nt * 128 + wn * 64 + (lane & 15);
#pragma unroll
  for (int i = 0; i < 4; i++)
#pragma unroll
    for (int r = 0; r < 4; r++) {
      int rr = mt * 128 + orow0 + i * 16 + r;
      if (rr < ce) {
        size_t rowoff = (size_t)(base + rr) * FF + ocol0;
#pragma unroll
        for (int j = 0; j < 4; j++) {
          float v = acc[i][j][r];
          if (GPASS) {
            float u = __bfloat162float(act[rowoff + j * 16]);
            v = 0.5f * v * (1.f + erff(v * 0.70710678118f)) * u;
          }
          act[rowoff + j * 16] = __float2bfloat16(v);
        }
      }
    }
}

// ---------------- FFN2: out += wt * (act @ W2^T), split-K x4, 2-phase
__global__ __launch_bounds__(256) void k_ffn2(
    const __hip_bfloat16* __restrict__ act, const __hip_bfloat16* __restrict__ w2b,
    const int* __restrict__ cnt, const int* __restrict__ tok,
    const float* __restrict__ wt, float* __restrict__ out)
{
  const int e  = blockIdx.z >> 2;
  const int sk = blockIdx.z & 3;
  const int mt = blockIdx.y;
  const int nt = blockIdx.x;
  const int ce = cnt[e];
  if (mt * 128 >= ce) return;
  int base = 0;
  for (int i = 0; i < e; i++) base += cnt[i];

  __shared__ short As[2][128 * BK];
  __shared__ short Bs[2][128 * BK];

  const int tid  = threadIdx.x;
  const int lane = tid & 63;
  const int wid  = tid >> 6;
  const int wm   = wid >> 1;
  const int wn   = wid & 1;

  const int srow = (wid << 3) + (lane >> 3);
  const int scol = SWZCOL(lane);
  const __hip_bfloat16* asrc[4];
#pragma unroll
  for (int i = 0; i < 4; i++) {
    int pos = mt * 128 + i * 32 + srow;
    int rc  = min(pos, ce - 1);
    asrc[i] = act + (size_t)(base + rc) * FF + (sk << 10) + scol;
  }
  const __hip_bfloat16* bsrc[4];
#pragma unroll
  for (int i = 0; i < 4; i++) {
    int hr = nt * 128 + i * 32 + srow;
    bsrc[i] = w2b + ((size_t)e * HH + hr) * FF + (sk << 10) + scol;
  }

  f4 acc[4][4];
#pragma unroll
  for (int i = 0; i < 4; i++)
#pragma unroll
    for (int j = 0; j < 4; j++) { f4 z = {0.f,0.f,0.f,0.f}; acc[i][j] = z; }

  const int xorv = lane & 7;
  const int hi   = lane >> 4;
  const int frow = lane & 15;

  STAGE1(0, 0);   // same macro shape: asrc/bsrc/As/Bs names match
  int cur = 0;
  const int NT = 1024 / BK;             // 16
  for (int t = 0; t < NT; t++) {
    if (t + 1 < NT) {
      STAGE1((t + 1) * BK, cur ^ 1);
      asm volatile("s_waitcnt vmcnt(8)" ::: "memory");
    } else {
      asm volatile("s_waitcnt vmcnt(0)" ::: "memory");
    }
    __builtin_amdgcn_s_barrier();
    __builtin_amdgcn_sched_barrier(0);
#pragma unroll
    for (int ks = 0; ks < 2; ks++) {
      const int col = (((ks << 2) + hi) ^ xorv) << 3;
      s8 af[4], bf_[4];
#pragma unroll
      for (int i = 0; i < 4; i++)
        af[i]  = *(const s8*)&As[cur][(wm * 64 + i * 16 + frow) * BK + col];
#pragma unroll
      for (int j = 0; j < 4; j++)
        bf_[j] = *(const s8*)&Bs[cur][(wn * 64 + j * 16 + frow) * BK + col];
#pragma unroll
      for (int i = 0; i < 4; i++)
#pragma unroll
        for (int j = 0; j < 4; j++)
          acc[i][j] = __builtin_amdgcn_mfma_f32_16x16x32_bf16(af[i], bf_[j], acc[i][j], 0, 0, 0);
    }
    __builtin_amdgcn_sched_barrier(0);
    __builtin_amdgcn_s_barrier();
    cur ^= 1;
  }

  const int orow0 = wm * 64 + ((lane >> 4) << 2);
  const int ocol0 = nt * 128 + wn * 64 + (lane & 15);
#pragma unroll
  for (int i = 0; i < 4; i++)
#pragma unroll
    for (int r = 0; r < 4; r++) {
      int rr = mt * 128 + orow0 + i * 16 + r;
      if (rr < ce) {
        int   tkn = tok[e * TT + rr];
        float w   = wt [e * TT + rr];
        float* orow = out + (size_t)tkn * HH + ocol0;
#pragma unroll
        for (int j = 0; j < 4; j++)
          atomicAdd(&orow[j * 16], acc[i][j][r] * w);
      }
    }
}

extern "C" void kernel_launch(void* const* d_in, const int* in_sizes, int n_in,
                              void* d_out, int out_size, void* d_ws, size_t ws_size,
                              hipStream_t stream)
{
  (void)in_sizes; (void)n_in; (void)ws_size;
  const float* h  = (const float*)d_in[0];
  const float* gw = (const float*)d_in[1];
  const float* w1 = (const float*)d_in[2];
  const float* w2 = (const float*)d_in[3];
  const float* w3 = (const float*)d_in[4];
  float* out = (float*)d_out;

  char* ws = (char*)d_ws;
  int*   cnt = (int*)ws;                             // 32 B
  int*   tok = (int*)(ws + 1024);                    // 64 KB
  float* wtp = (float*)(ws + 1024 + 65536);          // 64 KB
  __hip_bfloat16* act = (__hip_bfloat16*)(ws + 262144);            // 32 MB
  __hip_bfloat16* hb  = (__hip_bfloat16*)(ws + 262144 + 33554432); // 4 MB
  __hip_bfloat16* w1b = hb  + (size_t)TT * HH;                     // 64 MB
  __hip_bfloat16* w3b = w1b + (size_t)NE * FF * HH;                // 64 MB
  __hip_bfloat16* w2b = w3b + (size_t)NE * FF * HH;                // 64 MB

  hipMemsetAsync(cnt, 0, 32, stream);
  hipMemsetAsync(d_out, 0, (size_t)out_size * sizeof(float), stream);

  k_cvt<<<dim3(1024), dim3(256), 0, stream>>>(h,  hb,  TT * HH / 8);
  k_cvt<<<dim3(4096), dim3(256), 0, stream>>>(w1, w1b, NE * FF * HH / 8);
  k_cvt<<<dim3(4096), dim3(256), 0, stream>>>(w3, w3b, NE * FF * HH / 8);
  k_cvt<<<dim3(4096), dim3(256), 0, stream>>>(w2, w2b, NE * HH * FF / 8);

  k_router<<<dim3(TT / 4), dim3(256), 0, stream>>>(h, gw, cnt, tok, wtp);

  k_ffn1<false><<<dim3(FF / 128, 16, NE), dim3(256), 0, stream>>>(hb, w3b, cnt, tok, act);
  k_ffn1<true ><<<dim3(FF / 128, 16, NE), dim3(256), 0, stream>>>(hb, w1b, cnt, tok, act);
  k_ffn2<<<dim3(HH / 128, 16, NE * 4), dim3(256), 0, stream>>>(act, w2b, cnt, tok, wtp, out);
}